// Round 9
// baseline (1326.727 us; speedup 1.0000x reference)
//
#include <hip/hip_runtime.h>
#include <hip/hip_bf16.h>
#include <cmath>

// ============================================================================
// System2Graph fused pipeline, MI355X (gfx950) — round 9
// Image GEMMs: A operand loaded global->reg->split (no LDS round-trip);
// LDS holds only B (triple-buffered GLL16, counted vmcnt). 48KB LDS ->
// 3 blocks/CU. Numerically identical to rounds 7/8 (absmax 0).
// ws budget: 142,622,720 bytes.
// ============================================================================

typedef __bf16 bf16x8 __attribute__((ext_vector_type(8)));
typedef float  f32x4  __attribute__((ext_vector_type(4)));

__device__ __forceinline__ float gelu_f(float v) {
    return 0.5f * v * (1.0f + erff(v * 0.7071067811865476f));
}

__device__ __forceinline__ void split8(const float* v, bf16x8& H, bf16x8& L) {
#pragma unroll
    for (int j = 0; j < 8; ++j) {
        float x = v[j];
        __bf16 h = (__bf16)x;
        H[j] = h;
        L[j] = (__bf16)(x - (float)h);
    }
}

#define GLL16(src, dst)                                                        \
    __builtin_amdgcn_global_load_lds(                                          \
        (const __attribute__((address_space(1))) void*)(src),                  \
        (__attribute__((address_space(3))) void*)(dst), 16, 0, 0)

// XCD-chunked bijective remap; requires gridDim product % 8 == 0.
#define SWZ_DECODE()                                                           \
    int bx, by, bz;                                                            \
    {                                                                          \
        const int nx = gridDim.x, ny = gridDim.y;                              \
        const int nwg = nx * ny * (int)gridDim.z;                              \
        const int bid = blockIdx.x + nx * (blockIdx.y + ny * blockIdx.z);      \
        const int q = nwg >> 3;                                                \
        const int rm = (bid & 7) * q + (bid >> 3);                             \
        bx = rm % nx; by = (rm / nx) % ny; bz = rm / (nx * ny);                \
    }

#define WAIT_VM(N)                                                             \
    asm volatile("s_waitcnt vmcnt(" #N ")" ::: "memory");                      \
    __builtin_amdgcn_sched_barrier(0);

// ---------------------------------------------------------------------------
// Image tile layout: per (f, colTile ct, kTile kt): 16 KB (hi 8K | lo 8K);
// unit(col, g) at col*64 + ((g ^ ((col>>1)&3))<<4), 8 bf16 of k.
// Tile base = (((f*8 + ct) << nktLog) + kt) * 16384.
// ---------------------------------------------------------------------------
__global__ __launch_bounds__(256) void precvt_img(
    const float* __restrict__ W, char* __restrict__ img,
    int krowBase, int nktLog, int sumFromKt)
{
    const int u = blockIdx.x * 256 + threadIdx.x;
    const int col = u & 127;
    const int kt  = (u >> 7) & ((1 << nktLog) - 1);
    const int ct  = (u >> (7 + nktLog)) & 7;
    const int f   = u >> (10 + nktLog);
    const int colg = ct * 128 + col;
    const float* Wf = W + (size_t)f * 3072 * 1024;
    const bool sum2 = (kt >= sumFromKt);

    float vv[32];
#pragma unroll
    for (int j = 0; j < 32; ++j) {
        int k = krowBase + kt * 32 + j;
        float v = Wf[(size_t)k * 1024 + colg];
        if (sum2) v += Wf[(size_t)(k + 1024) * 1024 + colg];
        vv[j] = v;
    }
    char* tb = img + ((((size_t)f * 8 + ct) << nktLog) + kt) * 16384;
    const int swz = (col >> 1) & 3;
#pragma unroll
    for (int g = 0; g < 4; ++g) {
        bf16x8 H, L; split8(&vv[g * 8], H, L);
        char* dst = tb + col * 64 + ((g ^ swz) << 4);
        *(bf16x8*)dst = H;
        *(bf16x8*)(dst + 8192) = L;
    }
}

// ---------------------------------------------------------------------------
// Image-GEMM shared macros. LDS: B0 [0,16K) | B1 | B2  (48 KB total).
// A: global->reg (araw) -> split (ahC/alC) per kt, 2-deep pipelined.
// ---------------------------------------------------------------------------
#define LOADB_IMG(KT, BB)                                                      \
    {                                                                          \
        const char* sb = Bt + (size_t)(KT) * 16384 + boff;                     \
        char* db = (BB) + boff;                                                \
        GLL16(sb,        db);                                                  \
        GLL16(sb + 1024, db + 1024);                                           \
        GLL16(sb + 2048, db + 2048);                                           \
        GLL16(sb + 3072, db + 3072);                                           \
    }

#define SPLIT4()                                                               \
    _Pragma("unroll")                                                          \
    for (int mi = 0; mi < 4; ++mi) split8(araw[mi], ahC[mi], alC[mi]);

#define MFMA32REG(BB)                                                          \
    {                                                                          \
        bf16x8 bh[4], bl_[4];                                                  \
        _Pragma("unroll")                                                      \
        for (int ni = 0; ni < 4; ++ni) {                                       \
            const char* pb = (BB) + (wc + ni * 16 + rl) * 64 + goff;           \
            bh[ni]  = *(const bf16x8*)pb;                                      \
            bl_[ni] = *(const bf16x8*)(pb + 8192);                             \
        }                                                                      \
        _Pragma("unroll")                                                      \
        for (int mi = 0; mi < 4; ++mi)                                         \
            _Pragma("unroll")                                                  \
            for (int ni = 0; ni < 4; ++ni) {                                   \
                acc[mi][ni] = __builtin_amdgcn_mfma_f32_16x16x32_bf16(ahC[mi], bh[ni],  acc[mi][ni], 0, 0, 0); \
                acc[mi][ni] = __builtin_amdgcn_mfma_f32_16x16x32_bf16(ahC[mi], bl_[ni], acc[mi][ni], 0, 0, 0); \
                acc[mi][ni] = __builtin_amdgcn_mfma_f32_16x16x32_bf16(alC[mi], bh[ni],  acc[mi][ni], 0, 0, 0); \
            }                                                                  \
    }

// Pipeline. Loop invariant at iter kt top (post-barrier): B(kt) complete in
// Bc0; in flight (oldest->newest): B(kt+1) [4] then A(kt+1) [8]; ahC/alC =
// A(kt) split. Waits: vmcnt(4) drains B(kt+1)+A(kt+1), leaves B(kt+2).
#define PIPE_LOOP_R(NKT, LOADA_MACRO)                                          \
    LOADA_MACRO(0)                                                             \
    LOADB_IMG(0, Bc0)                                                          \
    LOADB_IMG(1, Bc1)                                                          \
    WAIT_VM(4)                                                                 \
    SPLIT4()                                                                   \
    LOADA_MACRO(1)                                                             \
    __builtin_amdgcn_s_barrier();                                              \
    for (int kt = 0; kt < (NKT); ++kt) {                                       \
        if (kt + 2 < (NKT)) { LOADB_IMG(kt + 2, Bc2) }                         \
        MFMA32REG(Bc0)                                                         \
        if (kt + 1 < (NKT)) {                                                  \
            if (kt + 2 < (NKT)) { WAIT_VM(4) } else { WAIT_VM(0) }             \
            SPLIT4()                                                           \
            if (kt + 2 < (NKT)) { LOADA_MACRO(kt + 2) }                        \
            __builtin_amdgcn_s_barrier();                                      \
        }                                                                      \
        char* bt = Bc0; Bc0 = Bc1; Bc1 = Bc2; Bc2 = bt;                        \
    }

// ---------------------------------------------------------------------------
// gemm_img: C[z] = A[rowBase + rows][1024] @ img[fimgBase + z]  (K=1024, 32 kt)
// ---------------------------------------------------------------------------
__global__ __launch_bounds__(256, 3) void gemm_img(
    const float* __restrict__ A, int rowBase,
    const char* __restrict__ img, int fimgBase,
    float* __restrict__ C, size_t cStrideZ)
{
    __shared__ __align__(16) char lds[49152];
    const int tid = threadIdx.x, wid = tid >> 6, lane = tid & 63;
    SWZ_DECODE();
    const int bm0 = bx * 128, bn0 = by * 128;
    const int fimg = fimgBase + bz;
    const char* Bt = img + (size_t)((fimg * 8 + by) << 5) * 16384;
    float* Cp = C + (size_t)bz * cStrideZ;
    const int wr = (wid >> 1) * 64, wc = (wid & 1) * 64;
    const int g = lane >> 4, rl = lane & 15;
    const int goff = ((g ^ ((rl >> 1) & 3)) << 4);
    const int boff = wid * 4096 + lane * 16;
    char* Bc0 = lds; char* Bc1 = lds + 16384; char* Bc2 = lds + 32768;

    // per-lane A base: row = rowBase + bm0 + wr + rl (+ mi*16), col = g*8 (+ kt*32)
    const float* aBase = A + (size_t)(rowBase + bm0 + wr + rl) * 1024 + g * 8;
    float araw[4][8];
    bf16x8 ahC[4], alC[4];
#define LOADA_R(KT)                                                            \
    {                                                                          \
        const float* s0 = aBase + (KT) * 32;                                   \
        _Pragma("unroll")                                                      \
        for (int mi = 0; mi < 4; ++mi) {                                       \
            const float* s = s0 + mi * 16384;                                  \
            *(float4*)&araw[mi][0] = ((const float4*)s)[0];                    \
            *(float4*)&araw[mi][4] = ((const float4*)s)[1];                    \
        }                                                                      \
    }

    f32x4 acc[4][4];
    f32x4 zero = {0.f, 0.f, 0.f, 0.f};
#pragma unroll
    for (int i = 0; i < 4; ++i)
#pragma unroll
        for (int j = 0; j < 4; ++j) acc[i][j] = zero;

    PIPE_LOOP_R(32, LOADA_R)
#undef LOADA_R

    const int cg = lane & 15, rg = (lane >> 4) * 4;
#pragma unroll
    for (int mi = 0; mi < 4; ++mi)
#pragma unroll
        for (int i = 0; i < 4; ++i) {
            int row_out = bm0 + wr + mi * 16 + rg + i;
#pragma unroll
            for (int ni = 0; ni < 4; ++ni) {
                int col = bn0 + wc + ni * 16 + cg;
                Cp[(size_t)row_out * 1024 + col] = acc[mi][ni][i];
            }
        }
}

// ---------------------------------------------------------------------------
// gate_img: T = [x | arg_f] @ WgImg (K=2048, 64 kt); epilogue:
// g2[z] (+)= fw[:,f] * sigmoid(T + bg[f]),  f = fbase + z.
// ---------------------------------------------------------------------------
__global__ __launch_bounds__(256, 3) void gate_img(
    const float* __restrict__ x, const float* __restrict__ arg,
    const char* __restrict__ img, const float* __restrict__ fw,
    const float* __restrict__ bg, float* __restrict__ g2, int fbase)
{
    __shared__ __align__(16) char lds[49152];
    const int tid = threadIdx.x, wid = tid >> 6, lane = tid & 63;
    SWZ_DECODE();
    const int bm0 = bx * 128, bn0 = by * 128;
    const int z = bz, f = fbase + z;
    const float* argf = arg + (size_t)f * 4096 * 1024;
    const char* Bt = img + (size_t)((f * 8 + by) << 6) * 16384;
    const int wr = (wid >> 1) * 64, wc = (wid & 1) * 64;
    const int g = lane >> 4, rl = lane & 15;
    const int goff = ((g ^ ((rl >> 1) & 3)) << 4);
    const int boff = wid * 4096 + lane * 16;
    char* Bc0 = lds; char* Bc1 = lds + 16384; char* Bc2 = lds + 32768;

    const size_t rowoff = (size_t)(bm0 + wr + rl) * 1024 + g * 8;
    const float* xab = x + rowoff;               // + kt*32 for kt < 32
    const float* aab = argf + rowoff - 1024;     // + kt*32 for kt >= 32
    float araw[4][8];
    bf16x8 ahC[4], alC[4];
#define LOADA_G(KT)                                                            \
    {                                                                          \
        const int k0g = (KT) * 32;                                             \
        const float* s0 = (k0g < 1024 ? xab : aab) + k0g;                      \
        _Pragma("unroll")                                                      \
        for (int mi = 0; mi < 4; ++mi) {                                       \
            const float* s = s0 + mi * 16384;                                  \
            *(float4*)&araw[mi][0] = ((const float4*)s)[0];                    \
            *(float4*)&araw[mi][4] = ((const float4*)s)[1];                    \
        }                                                                      \
    }

    f32x4 acc[4][4];
    f32x4 zero = {0.f, 0.f, 0.f, 0.f};
#pragma unroll
    for (int i = 0; i < 4; ++i)
#pragma unroll
        for (int j = 0; j < 4; ++j) acc[i][j] = zero;

    PIPE_LOOP_R(64, LOADA_G)
#undef LOADA_G

    const int cg = lane & 15, rg = (lane >> 4) * 4;
    const bool accum = (fbase > 0);
#pragma unroll
    for (int mi = 0; mi < 4; ++mi)
#pragma unroll
        for (int i = 0; i < 4; ++i) {
            int row_out = bm0 + wr + mi * 16 + rg + i;
            float fwv = fw[(size_t)row_out * 4 + f];
#pragma unroll
            for (int ni = 0; ni < 4; ++ni) {
                int col = bn0 + wc + ni * 16 + cg;
                float v = acc[mi][ni][i] + bg[f * 1024 + col];
                float s = fwv / (1.0f + expf(-v));
                size_t off = ((size_t)z * 4096 + row_out) * 1024 + col;
                if (accum) g2[off] += s; else g2[off] = s;
            }
        }
}

// ---------------------------------------------------------------------------
// deproj_part: K-split x4 partials of de_proj = dtab @ Wl[f][2048:3072].
// ---------------------------------------------------------------------------
#define STAGE_WRITE64()                                                        \
    _Pragma("unroll")                                                          \
    for (int i = 0; i < 4; ++i) {                                              \
        int u = tid + i * 256;                                                 \
        int arow = u >> 3, ag = u & 7;                                         \
        bf16x8 H, L; split8(rav[i], H, L);                                     \
        char* dst = lds + arow * 128 + ((ag ^ (arow & 7)) << 4);               \
        *(bf16x8*)dst = H; *(bf16x8*)(dst + 16384) = L;                        \
    }                                                                          \
    _Pragma("unroll")                                                          \
    for (int i = 0; i < 4; ++i) {                                              \
        int u = tid + i * 256;                                                 \
        int bcol = u & 127, bgu = u >> 7;                                      \
        bf16x8 H, L; split8(rbv[i], H, L);                                     \
        char* dst = lds + 32768 + bcol * 128 + ((bgu ^ (bcol & 7)) << 4);      \
        *(bf16x8*)dst = H; *(bf16x8*)(dst + 16384) = L;                        \
    }

#define MFMA64()                                                               \
    _Pragma("unroll")                                                          \
    for (int ks2 = 0; ks2 < 2; ++ks2) {                                        \
        bf16x8 ah[4], al[4], bh[4], bl_[4];                                    \
        _Pragma("unroll")                                                      \
        for (int mi = 0; mi < 4; ++mi) {                                       \
            const char* pa = lds + (wr + mi * 16 + rl) * 128                   \
                             + (((ks2 * 4 + g) ^ (rl & 7)) << 4);              \
            ah[mi] = *(const bf16x8*)pa;                                       \
            al[mi] = *(const bf16x8*)(pa + 16384);                             \
        }                                                                      \
        _Pragma("unroll")                                                      \
        for (int ni = 0; ni < 4; ++ni) {                                       \
            const char* pb = lds + 32768 + (wc + ni * 16 + rl) * 128           \
                             + (((ks2 * 4 + g) ^ (rl & 7)) << 4);              \
            bh[ni]  = *(const bf16x8*)pb;                                      \
            bl_[ni] = *(const bf16x8*)(pb + 16384);                            \
        }                                                                      \
        _Pragma("unroll")                                                      \
        for (int mi = 0; mi < 4; ++mi)                                         \
            _Pragma("unroll")                                                  \
            for (int ni = 0; ni < 4; ++ni) {                                   \
                acc[mi][ni] = __builtin_amdgcn_mfma_f32_16x16x32_bf16(ah[mi], bh[ni],  acc[mi][ni], 0, 0, 0); \
                acc[mi][ni] = __builtin_amdgcn_mfma_f32_16x16x32_bf16(ah[mi], bl_[ni], acc[mi][ni], 0, 0, 0); \
                acc[mi][ni] = __builtin_amdgcn_mfma_f32_16x16x32_bf16(al[mi], bh[ni],  acc[mi][ni], 0, 0, 0); \
            }                                                                  \
    }

__global__ __launch_bounds__(256, 2) void deproj_part(
    const float* __restrict__ dtab, const float* __restrict__ Wl,
    float* __restrict__ pbase)
{
    __shared__ __align__(16) char lds[65536];
    const int tid = threadIdx.x, wid = tid >> 6, lane = tid & 63;
    SWZ_DECODE();
    const int bm0 = bx * 128, bn0 = by * 128;
    const int f = bz & 3, ks = bz >> 2;
    const int akb = ks * 256;
    const float* Bf = Wl + (size_t)f * 3072 * 1024 + (size_t)(2048 + ks * 256) * 1024;
    float* Cp = pbase + (size_t)ks * 2101248 + (size_t)f * 525312;
    const int wr = (wid >> 1) * 64, wc = (wid & 1) * 64;
    const int g = lane >> 4, rl = lane & 15;

    float rav[4][8], rbv[4][8];

#define LOADA_D(KC0)                                                           \
    _Pragma("unroll")                                                          \
    for (int i = 0; i < 4; ++i) {                                              \
        int u = tid + i * 256;                                                 \
        int r = bm0 + (u >> 3); if (r > 512) r = 512;                          \
        const float* s = dtab + (size_t)r * 1024 + akb + (KC0) + (u & 7) * 8;  \
        *(float4*)&rav[i][0] = ((const float4*)s)[0];                          \
        *(float4*)&rav[i][4] = ((const float4*)s)[1];                          \
    }
#define LOADB_D(KC0)                                                           \
    _Pragma("unroll")                                                          \
    for (int i = 0; i < 4; ++i) {                                              \
        int u = tid + i * 256;                                                 \
        int bcol = bn0 + (u & 127);                                            \
        int k0 = (KC0) + (u >> 7) * 8;                                         \
        _Pragma("unroll")                                                      \
        for (int j = 0; j < 8; ++j)                                            \
            rbv[i][j] = Bf[(size_t)(k0 + j) * 1024 + bcol];                    \
    }

    f32x4 acc[4][4];
    f32x4 zero = {0.f, 0.f, 0.f, 0.f};
#pragma unroll
    for (int i = 0; i < 4; ++i)
#pragma unroll
        for (int j = 0; j < 4; ++j) acc[i][j] = zero;

    LOADA_D(0) LOADB_D(0)
    for (int kt = 0; kt < 4; ++kt) {
        STAGE_WRITE64()
        __syncthreads();
        if (kt + 1 < 4) { LOADA_D((kt + 1) * 64) LOADB_D((kt + 1) * 64) }
        MFMA64()
        __syncthreads();
    }
#undef LOADA_D
#undef LOADB_D

    const int cg = lane & 15, rg = (lane >> 4) * 4;
#pragma unroll
    for (int mi = 0; mi < 4; ++mi)
#pragma unroll
        for (int i = 0; i < 4; ++i) {
            int row_out = bm0 + wr + mi * 16 + rg + i;
            if (row_out >= 513) continue;
#pragma unroll
            for (int ni = 0; ni < 4; ++ni) {
                int col = bn0 + wc + ni * 16 + cg;
                Cp[(size_t)row_out * 1024 + col] = acc[mi][ni][i];
            }
        }
}

// de_proj = ((p0 + p1) + p2) + p3  (fixed order, deterministic)
__global__ __launch_bounds__(256) void deproj_reduce(float* __restrict__ p)
{
    const size_t i = ((size_t)blockIdx.x * 256 + threadIdx.x) * 4;
    float4 a = *(float4*)&p[i];
    float4 b = *(const float4*)&p[i + 2101248];
    float4 c = *(const float4*)&p[i + 4202496];
    float4 d = *(const float4*)&p[i + 6303744];
    a.x = ((a.x + b.x) + c.x) + d.x;
    a.y = ((a.y + b.y) + c.y) + d.y;
    a.z = ((a.z + b.z) + c.z) + d.z;
    a.w = ((a.w + b.w) + c.w) + d.w;
    *(float4*)&p[i] = a;
}

// ---------------------------------------------------------------------------
// fw[n][0..3] = softmax(x[n] @ Wsel + bsel)
// ---------------------------------------------------------------------------
__global__ __launch_bounds__(256) void fw_kernel(
    const float* __restrict__ x, const float* __restrict__ Wsel,
    const float* __restrict__ bsel, float* __restrict__ fw)
{
    __shared__ float sred[16];
    const int n = blockIdx.x;
    const int tid = threadIdx.x, w = tid >> 6, lane = tid & 63;

    float4 xv = *(const float4*)&x[(size_t)n * 1024 + tid * 4];
    float pf0 = 0, pf1 = 0, pf2 = 0, pf3 = 0;
    const float* wrp = &Wsel[(size_t)tid * 16];
    pf0 += xv.x * wrp[0];  pf1 += xv.x * wrp[1];  pf2 += xv.x * wrp[2];  pf3 += xv.x * wrp[3];
    pf0 += xv.y * wrp[4];  pf1 += xv.y * wrp[5];  pf2 += xv.y * wrp[6];  pf3 += xv.y * wrp[7];
    pf0 += xv.z * wrp[8];  pf1 += xv.z * wrp[9];  pf2 += xv.z * wrp[10]; pf3 += xv.z * wrp[11];
    pf0 += xv.w * wrp[12]; pf1 += xv.w * wrp[13]; pf2 += xv.w * wrp[14]; pf3 += xv.w * wrp[15];
    for (int o = 32; o; o >>= 1) {
        pf0 += __shfl_xor(pf0, o); pf1 += __shfl_xor(pf1, o);
        pf2 += __shfl_xor(pf2, o); pf3 += __shfl_xor(pf3, o);
    }
    if (lane == 0) { sred[w*4+0] = pf0; sred[w*4+1] = pf1; sred[w*4+2] = pf2; sred[w*4+3] = pf3; }
    __syncthreads();
    if (tid == 0) {
        float s0 = sred[0] + sred[4] + sred[8]  + sred[12] + bsel[0];
        float s1 = sred[1] + sred[5] + sred[9]  + sred[13] + bsel[1];
        float s2 = sred[2] + sred[6] + sred[10] + sred[14] + bsel[2];
        float s3 = sred[3] + sred[7] + sred[11] + sred[15] + bsel[3];
        float mx = fmaxf(fmaxf(s0, s1), fmaxf(s2, s3));
        float e0 = expf(s0 - mx), e1 = expf(s1 - mx), e2 = expf(s2 - mx), e3 = expf(s3 - mx);
        float inv = 1.0f / (e0 + e1 + e2 + e3);
        float4 o = { e0 * inv, e1 * inv, e2 * inv, e3 * inv };
        *(float4*)&fw[(size_t)n * 4] = o;
    }
}

// ---------------------------------------------------------------------------
// h = hpre + xl + de_proj[idx] + bl -> GELU -> LN -> *g+b; arg = sum_k sw*h
// xl aliases the output row (arg[f,n]) — read-before-write within the block.
// ---------------------------------------------------------------------------
__global__ __launch_bounds__(256) void ln_fuse_kernel(
    const float* __restrict__ hpre, const float* __restrict__ de_proj,
    const float* __restrict__ bl, const float* __restrict__ ln_g,
    const float* __restrict__ ln_b, const float* __restrict__ sim,
    const int* __restrict__ topk, float* arg,
    int f, int token_base, const float* xl)
{
    __shared__ float red[4 * 1024];
    const int n = token_base + blockIdx.x;
    const int k = threadIdx.x >> 6, lane = threadIdx.x & 63;
    const float* hrow = hpre + ((size_t)blockIdx.x * 4 + k) * 1024;
    const int t  = n & 1023;
    const int tk = topk[(size_t)n * 4 + k];
    int di = t - tk + 256; di = di < 0 ? 0 : (di > 512 ? 512 : di);
    const float* drow = de_proj + ((size_t)f * 513 + di) * 1024;
    const float* blr = bl + f * 1024;
    const float* gr  = ln_g + f * 1024;
    const float* br  = ln_b + f * 1024;
    const float* xr  = xl + (size_t)n * 1024;

    float4 s4 = *(const float4*)&sim[(size_t)n * 4];
    float smax = fmaxf(fmaxf(s4.x, s4.y), fmaxf(s4.z, s4.w));
    float e0 = expf(s4.x - smax), e1 = expf(s4.y - smax);
    float e2 = expf(s4.z - smax), e3 = expf(s4.w - smax);
    float swk = (k == 0 ? e0 : k == 1 ? e1 : k == 2 ? e2 : e3) / (e0 + e1 + e2 + e3);

    float gv[16];
    float ssum = 0.f;
#pragma unroll
    for (int j = 0; j < 4; ++j) {
        int d4 = lane + j * 64;
        float4 h  = *(const float4*)&hrow[d4 * 4];
        float4 dd = *(const float4*)&drow[d4 * 4];
        float4 bb = *(const float4*)&blr[d4 * 4];
        float4 xv = *(const float4*)&xr[d4 * 4];
        float a0 = gelu_f(h.x + xv.x + dd.x + bb.x);
        float a1 = gelu_f(h.y + xv.y + dd.y + bb.y);
        float a2 = gelu_f(h.z + xv.z + dd.z + bb.z);
        float a3 = gelu_f(h.w + xv.w + dd.w + bb.w);
        gv[j*4+0] = a0; gv[j*4+1] = a1; gv[j*4+2] = a2; gv[j*4+3] = a3;
        ssum += a0 + a1 + a2 + a3;
    }
    for (int o = 32; o; o >>= 1) ssum += __shfl_xor(ssum, o);
    float mu = ssum * 0.0009765625f;
    float vs = 0.f;
#pragma unroll
    for (int i = 0; i < 16; ++i) { float dm = gv[i] - mu; vs += dm * dm; }
    for (int o = 32; o; o >>= 1) vs += __shfl_xor(vs, o);
    float rstd = 1.0f / sqrtf(vs * 0.0009765625f + 1e-5f);
#pragma unroll
    for (int j = 0; j < 4; ++j) {
        int d4 = lane + j * 64;
        float4 g4 = *(const float4*)&gr[d4 * 4];
        float4 b4 = *(const float4*)&br[d4 * 4];
        float4 y;
        y.x = ((gv[j*4+0] - mu) * rstd * g4.x + b4.x) * swk;
        y.y = ((gv[j*4+1] - mu) * rstd * g4.y + b4.y) * swk;
        y.z = ((gv[j*4+2] - mu) * rstd * g4.z + b4.z) * swk;
        y.w = ((gv[j*4+3] - mu) * rstd * g4.w + b4.w) * swk;
        *(float4*)&red[k * 1024 + d4 * 4] = y;
    }
    __syncthreads();
    const int p = threadIdx.x;
    float4 r0 = *(const float4*)&red[0 * 1024 + p * 4];
    float4 r1 = *(const float4*)&red[1 * 1024 + p * 4];
    float4 r2 = *(const float4*)&red[2 * 1024 + p * 4];
    float4 r3 = *(const float4*)&red[3 * 1024 + p * 4];
    float4 o;
    o.x = r0.x + r1.x + r2.x + r3.x;
    o.y = r0.y + r1.y + r2.y + r3.y;
    o.z = r0.z + r1.z + r2.z + r3.z;
    o.w = r0.w + r1.w + r2.w + r3.w;
    *(float4*)&arg[((size_t)f * 4096 + n) * 1024 + p * 4] = o;
}

// ---------------------------------------------------------------------------
// uf = (sum_f fw*arg) * (g2[0]+g2[1]); VQ argmin over 32 codes; gather.
// ---------------------------------------------------------------------------
__global__ __launch_bounds__(256) void final_kernel(
    const float* __restrict__ fw, const float* __restrict__ arg,
    const float* __restrict__ g2, const float* __restrict__ cb,
    float* __restrict__ out)
{
    __shared__ float uf_s[1024];
    __shared__ float score_s[32];
    __shared__ int enc_s;
    const int n = blockIdx.x;
    const int tid = threadIdx.x, w = tid >> 6, lane = tid & 63;

    float4 fwv = *(const float4*)&fw[(size_t)n * 4];
    float fwa[4] = { fwv.x, fwv.y, fwv.z, fwv.w };

    float4 prop = {0, 0, 0, 0};
#pragma unroll
    for (int f = 0; f < 4; ++f) {
        float4 av = *(const float4*)&arg[((size_t)f * 4096 + n) * 1024 + tid * 4];
        prop.x += fwa[f] * av.x; prop.y += fwa[f] * av.y;
        prop.z += fwa[f] * av.z; prop.w += fwa[f] * av.w;
    }
    float4 ga = *(const float4*)&g2[(size_t)n * 1024 + tid * 4];
    float4 gb = *(const float4*)&g2[(size_t)(4096 + n) * 1024 + tid * 4];
    float4 uf;
    uf.x = prop.x * (ga.x + gb.x); uf.y = prop.y * (ga.y + gb.y);
    uf.z = prop.z * (ga.z + gb.z); uf.w = prop.w * (ga.w + gb.w);
    *(float4*)&uf_s[tid * 4] = uf;
    __syncthreads();

#pragma unroll
    for (int cc = 0; cc < 8; ++cc) {
        int c = w * 8 + cc;
        float p = 0.f, q = 0.f;
#pragma unroll
        for (int j = 0; j < 4; ++j) {
            int d4 = lane + j * 64;
            float4 u4 = *(const float4*)&uf_s[d4 * 4];
            float4 c4 = *(const float4*)&cb[(size_t)c * 1024 + d4 * 4];
            p += u4.x * c4.x + u4.y * c4.y + u4.z * c4.z + u4.w * c4.w;
            q += c4.x * c4.x + c4.y * c4.y + c4.z * c4.z + c4.w * c4.w;
        }
        float s = q - 2.0f * p;
        for (int o = 32; o; o >>= 1) s += __shfl_xor(s, o);
        if (lane == 0) score_s[c] = s;
    }
    __syncthreads();
    if (tid < 64) {
        float v; int idx;
        if (lane < 32) { v = score_s[lane]; idx = lane; }
        else           { v = INFINITY;      idx = 1 << 30; }
        for (int o = 16; o; o >>= 1) {
            float ov = __shfl_xor(v, o); int oi = __shfl_xor(idx, o);
            if (ov < v || (ov == v && oi < idx)) { v = ov; idx = oi; }
        }
        if (lane == 0) enc_s = idx;
    }
    __syncthreads();
    const int enc = enc_s;
    float4 o4 = *(const float4*)&cb[(size_t)enc * 1024 + tid * 4];
    *(float4*)&out[(size_t)n * 1024 + tid * 4] = o4;
}

// ---------------------------------------------------------------------------
extern "C" void kernel_launch(void* const* d_in, const int* in_sizes, int n_in,
                              void* d_out, int out_size, void* d_ws, size_t ws_size,
                              hipStream_t stream)
{
    const float* x    = (const float*)d_in[0];
    const float* rf   = (const float*)d_in[1];
    const float* sim  = (const float*)d_in[2];
    const float* Wl   = (const float*)d_in[3];
    const float* bl   = (const float*)d_in[4];
    const float* ln_g = (const float*)d_in[5];
    const float* ln_b = (const float*)d_in[6];
    const float* Wg   = (const float*)d_in[7];
    const float* bg   = (const float*)d_in[8];
    const float* Wsel = (const float*)d_in[9];
    const float* bsel = (const float*)d_in[10];
    const float* dtab = (const float*)d_in[11];
    const float* cb   = (const float*)d_in[12];
    const int*   topk = (const int*)d_in[13];
    float* out = (float*)d_out;
    dim3 blk(256);

    // ws layout (bytes), budget 142,622,720:
    //   arg     @ 0            67,108,864   (xl written in-place, then ln output)
    //   phase B:
    //     de_proj @ 67,108,864  8,404,992   (K-split partials extend into hbuf)
    //     hbuf    @ 75,513,856 33,554,432
    //     Wl1img  @109,068,288 16,777,216
    //     Wl0img  @125,845,504 16,777,216   (ends exactly at budget)
    //   phase C (B pool dead):
    //     Wgimg   @ 67,108,864 33,554,432
    //     g2      @100,663,296 33,554,432
    //     fw      @134,217,728     65,536
    const size_t NEED = 142622720ull;
    if (ws_size < NEED) return;
    char* ws = (char*)d_ws;
    float* arg     = (float*)(ws + 0);
    float* de_proj = (float*)(ws + 67108864);
    float* hbuf    = (float*)(ws + 75513856);
    char*  Wl1img  = ws + 109068288;
    char*  Wl0img  = ws + 125845504;
    char*  Wgimg   = ws + 67108864;
    float* g2      = (float*)(ws + 100663296);
    float* fw      = (float*)(ws + 134217728);

    // 1) de_proj partials (K-split x4, 640 blocks) + deterministic reduce
    deproj_part<<<dim3(5, 8, 16), blk, 0, stream>>>(dtab, Wl, de_proj);
    deproj_reduce<<<2052, blk, 0, stream>>>(de_proj);

    // 2) Wl0 image; xl4: arg[f] = x @ Wl0img[f]  (1024 blocks, image path)
    precvt_img<<<512, blk, 0, stream>>>(Wl, Wl0img, 0, 5, 99);
    gemm_img<<<dim3(32, 8, 4), blk, 0, stream>>>(
        x, 0, Wl0img, 0, arg, (size_t)4096 * 1024);

    // 3) Wl1 image
    precvt_img<<<512, blk, 0, stream>>>(Wl, Wl1img, 1024, 5, 99);

    // 4) per f, per chunk: h GEMM (image path) + fused GELU/LN/softmax-reduce
    for (int f = 0; f < 4; ++f) {
        const float* xlf = arg + (size_t)f * 4096 * 1024;
        for (int ch = 0; ch < 2; ++ch) {
            gemm_img<<<dim3(64, 8, 1), blk, 0, stream>>>(
                rf, ch * 8192, Wl1img, f, hbuf, 0);
            ln_fuse_kernel<<<2048, blk, 0, stream>>>(
                hbuf, de_proj, bl, ln_g, ln_b, sim, topk, arg,
                f, ch * 2048, xlf);
        }
    }

    // 5) Wg image (summed k>=1024) — phase-B pool dead
    precvt_img<<<1024, blk, 0, stream>>>(Wg, Wgimg, 0, 6, 32);

    // 6) fw = softmax(x @ Wsel + bsel)
    fw_kernel<<<4096, blk, 0, stream>>>(x, Wsel, bsel, fw);

    // 7) g2[z] = fw[:,z] * sigmoid([x|arg_z] @ Wg[z] + bg[z]); then += f=z+2
    gate_img<<<dim3(32, 8, 2), blk, 0, stream>>>(x, arg, Wgimg, fw, bg, g2, 0);
    gate_img<<<dim3(32, 8, 2), blk, 0, stream>>>(x, arg, Wgimg, fw, bg, g2, 2);

    // 8) uf = (sum_f fw*arg) * (g2[0]+g2[1]); VQ argmin; codebook gather
    final_kernel<<<4096, blk, 0, stream>>>(fw, arg, g2, cb, out);
}

// Round 10
// 948.931 us; speedup vs baseline: 1.3981x; 1.3981x over previous
//
#include <hip/hip_runtime.h>
#include <hip/hip_bf16.h>
#include <cmath>

// ============================================================================
// System2Graph fused pipeline, MI355X (gfx950) — round 10 (= round 8 revert)
// Image GEMMs: A staged via LDS (split in-kernel), B triple-buffered via
// global_load_lds with counted s_waitcnt vmcnt(8) + raw s_barrier (never
// vmcnt(0) in the main loop). Proven 949 us, absmax 0.
// ws budget: 142,622,720 bytes.
// ============================================================================

typedef __bf16 bf16x8 __attribute__((ext_vector_type(8)));
typedef float  f32x4  __attribute__((ext_vector_type(4)));

__device__ __forceinline__ float gelu_f(float v) {
    return 0.5f * v * (1.0f + erff(v * 0.7071067811865476f));
}

__device__ __forceinline__ void split8(const float* v, bf16x8& H, bf16x8& L) {
#pragma unroll
    for (int j = 0; j < 8; ++j) {
        float x = v[j];
        __bf16 h = (__bf16)x;
        H[j] = h;
        L[j] = (__bf16)(x - (float)h);
    }
}

#define GLL16(src, dst)                                                        \
    __builtin_amdgcn_global_load_lds(                                          \
        (const __attribute__((address_space(1))) void*)(src),                  \
        (__attribute__((address_space(3))) void*)(dst), 16, 0, 0)

// XCD-chunked bijective remap; requires gridDim product % 8 == 0.
#define SWZ_DECODE()                                                           \
    int bx, by, bz;                                                            \
    {                                                                          \
        const int nx = gridDim.x, ny = gridDim.y;                              \
        const int nwg = nx * ny * (int)gridDim.z;                              \
        const int bid = blockIdx.x + nx * (blockIdx.y + ny * blockIdx.z);      \
        const int q = nwg >> 3;                                                \
        const int rm = (bid & 7) * q + (bid >> 3);                             \
        bx = rm % nx; by = (rm / nx) % ny; bz = rm / (nx * ny);                \
    }

#define WAIT_VM(N)                                                             \
    asm volatile("s_waitcnt vmcnt(" #N ")" ::: "memory");                      \
    __builtin_amdgcn_sched_barrier(0);
#define WAIT_LGKM0()                                                           \
    asm volatile("s_waitcnt lgkmcnt(0)" ::: "memory");                         \
    __builtin_amdgcn_sched_barrier(0);

// ---------------------------------------------------------------------------
// Image tile layout: per (f, colTile ct, kTile kt): 16 KB (hi 8K | lo 8K);
// unit(col, g) at col*64 + ((g ^ ((col>>1)&3))<<4), 8 bf16 of k.
// Tile base = (((f*8 + ct) << nktLog) + kt) * 16384.
// ---------------------------------------------------------------------------
__global__ __launch_bounds__(256) void precvt_img(
    const float* __restrict__ W, char* __restrict__ img,
    int krowBase, int nktLog, int sumFromKt)
{
    const int u = blockIdx.x * 256 + threadIdx.x;
    const int col = u & 127;
    const int kt  = (u >> 7) & ((1 << nktLog) - 1);
    const int ct  = (u >> (7 + nktLog)) & 7;
    const int f   = u >> (10 + nktLog);
    const int colg = ct * 128 + col;
    const float* Wf = W + (size_t)f * 3072 * 1024;
    const bool sum2 = (kt >= sumFromKt);

    float vv[32];
#pragma unroll
    for (int j = 0; j < 32; ++j) {
        int k = krowBase + kt * 32 + j;
        float v = Wf[(size_t)k * 1024 + colg];
        if (sum2) v += Wf[(size_t)(k + 1024) * 1024 + colg];
        vv[j] = v;
    }
    char* tb = img + ((((size_t)f * 8 + ct) << nktLog) + kt) * 16384;
    const int swz = (col >> 1) & 3;
#pragma unroll
    for (int g = 0; g < 4; ++g) {
        bf16x8 H, L; split8(&vv[g * 8], H, L);
        char* dst = tb + col * 64 + ((g ^ swz) << 4);
        *(bf16x8*)dst = H;
        *(bf16x8*)(dst + 8192) = L;
    }
}

// ---------------------------------------------------------------------------
// Shared macros for image GEMMs.
// LDS: A0 [0,16K) | A1 [16K,32K) | B0 | B1 | B2  (80 KB total)
// ---------------------------------------------------------------------------
#define WRITEA_SPLIT(AB)                                                       \
    {                                                                          \
        int row = tid >> 2, ag = tid & 3;                                      \
        bf16x8 H, L; split8(ra[0], H, L);                                      \
        char* d = (AB) + row * 64 + ((ag ^ ((row >> 1) & 3)) << 4);            \
        *(bf16x8*)d = H; *(bf16x8*)(d + 8192) = L;                             \
        int row2 = row + 64;                                                   \
        split8(ra[1], H, L);                                                   \
        char* d2 = (AB) + row2 * 64 + ((ag ^ ((row2 >> 1) & 3)) << 4);         \
        *(bf16x8*)d2 = H; *(bf16x8*)(d2 + 8192) = L;                           \
    }

#define LOADB_IMG(KT, BB)                                                      \
    {                                                                          \
        const char* sb = Bt + (size_t)(KT) * 16384 + boff;                     \
        char* db = (BB) + boff;                                                \
        GLL16(sb,        db);                                                  \
        GLL16(sb + 1024, db + 1024);                                           \
        GLL16(sb + 2048, db + 2048);                                           \
        GLL16(sb + 3072, db + 3072);                                           \
    }

#define MFMA32(AB, BB)                                                         \
    {                                                                          \
        bf16x8 ah[4], al[4], bh[4], bl_[4];                                    \
        _Pragma("unroll")                                                      \
        for (int mi = 0; mi < 4; ++mi) {                                       \
            const char* pa = (AB) + (wr + mi * 16 + rl) * 64 + goff;           \
            ah[mi] = *(const bf16x8*)pa;                                       \
            al[mi] = *(const bf16x8*)(pa + 8192);                              \
        }                                                                      \
        _Pragma("unroll")                                                      \
        for (int ni = 0; ni < 4; ++ni) {                                       \
            const char* pb = (BB) + (wc + ni * 16 + rl) * 64 + goff;           \
            bh[ni]  = *(const bf16x8*)pb;                                      \
            bl_[ni] = *(const bf16x8*)(pb + 8192);                             \
        }                                                                      \
        _Pragma("unroll")                                                      \
        for (int mi = 0; mi < 4; ++mi)                                         \
            _Pragma("unroll")                                                  \
            for (int ni = 0; ni < 4; ++ni) {                                   \
                acc[mi][ni] = __builtin_amdgcn_mfma_f32_16x16x32_bf16(ah[mi], bh[ni],  acc[mi][ni], 0, 0, 0); \
                acc[mi][ni] = __builtin_amdgcn_mfma_f32_16x16x32_bf16(ah[mi], bl_[ni], acc[mi][ni], 0, 0, 0); \
                acc[mi][ni] = __builtin_amdgcn_mfma_f32_16x16x32_bf16(al[mi], bh[ni],  acc[mi][ni], 0, 0, 0); \
            }                                                                  \
    }

// Deep-pipelined K-loop body. Invariant at top of iter kt (post-barrier):
//   A(kt) in LDS (Ac), B(kt) complete (Bc0), in flight: A(kt+1) regs + B(kt+1).
#define PIPE_LOOP(NKT, LOADA_MACRO)                                            \
    LOADA_MACRO(0)                                                             \
    LOADB_IMG(0, Bc0)                                                          \
    WRITEA_SPLIT(Ac)                                                           \
    LOADA_MACRO(1)                                                             \
    LOADB_IMG(1, Bc1)                                                          \
    WAIT_VM(8)                                                                 \
    WAIT_LGKM0()                                                               \
    __builtin_amdgcn_s_barrier();                                              \
    for (int kt = 0; kt < (NKT); ++kt) {                                       \
        if (kt + 1 < (NKT)) { WRITEA_SPLIT(An) }                               \
        if (kt + 2 < (NKT)) { LOADA_MACRO(kt + 2) LOADB_IMG(kt + 2, Bc2) }     \
        MFMA32(Ac, Bc0)                                                        \
        if (kt + 1 < (NKT)) {                                                  \
            if (kt + 2 < (NKT)) { WAIT_VM(8) } else { WAIT_VM(0) }             \
            WAIT_LGKM0()                                                       \
            __builtin_amdgcn_s_barrier();                                      \
        }                                                                      \
        char* bt = Bc0; Bc0 = Bc1; Bc1 = Bc2; Bc2 = bt;                        \
        char* at = Ac; Ac = An; An = at;                                       \
    }

// ---------------------------------------------------------------------------
// gemm_img: C[z] = A[rowBase + rows][1024] @ img[fimgBase + z]  (K=1024, 32 kt)
// ---------------------------------------------------------------------------
__global__ __launch_bounds__(256, 2) void gemm_img(
    const float* __restrict__ A, int rowBase,
    const char* __restrict__ img, int fimgBase,
    float* __restrict__ C, size_t cStrideZ)
{
    __shared__ __align__(16) char lds[81920];
    const int tid = threadIdx.x, wid = tid >> 6, lane = tid & 63;
    SWZ_DECODE();
    const int bm0 = bx * 128, bn0 = by * 128;
    const int fimg = fimgBase + bz;
    const char* Bt = img + (size_t)((fimg * 8 + by) << 5) * 16384;
    float* Cp = C + (size_t)bz * cStrideZ;
    const int wr = (wid >> 1) * 64, wc = (wid & 1) * 64;
    const int g = lane >> 4, rl = lane & 15;
    const int goff = ((g ^ ((rl >> 1) & 3)) << 4);
    const int boff = wid * 4096 + lane * 16;
    char* Ac = lds;            char* An = lds + 16384;
    char* Bc0 = lds + 32768;   char* Bc1 = lds + 49152;   char* Bc2 = lds + 65536;

    const float* abase = A + (size_t)(rowBase + bm0 + (tid >> 2)) * 1024 + (tid & 3) * 8;
    float ra[2][8];
#define LOADA_H(KT)                                                            \
    {                                                                          \
        const float* s = abase + (KT) * 32;                                    \
        *(float4*)&ra[0][0] = ((const float4*)s)[0];                           \
        *(float4*)&ra[0][4] = ((const float4*)s)[1];                           \
        const float* s2 = s + 64 * 1024;                                       \
        *(float4*)&ra[1][0] = ((const float4*)s2)[0];                          \
        *(float4*)&ra[1][4] = ((const float4*)s2)[1];                          \
    }

    f32x4 acc[4][4];
    f32x4 zero = {0.f, 0.f, 0.f, 0.f};
#pragma unroll
    for (int i = 0; i < 4; ++i)
#pragma unroll
        for (int j = 0; j < 4; ++j) acc[i][j] = zero;

    PIPE_LOOP(32, LOADA_H)
#undef LOADA_H

    const int cg = lane & 15, rg = (lane >> 4) * 4;
#pragma unroll
    for (int mi = 0; mi < 4; ++mi)
#pragma unroll
        for (int i = 0; i < 4; ++i) {
            int row_out = bm0 + wr + mi * 16 + rg + i;
#pragma unroll
            for (int ni = 0; ni < 4; ++ni) {
                int col = bn0 + wc + ni * 16 + cg;
                Cp[(size_t)row_out * 1024 + col] = acc[mi][ni][i];
            }
        }
}

// ---------------------------------------------------------------------------
// gate_img: T = [x | arg_f] @ WgImg (K=2048, 64 kt); epilogue:
// g2[z] (+)= fw[:,f] * sigmoid(T + bg[f]),  f = fbase + z.
// ---------------------------------------------------------------------------
__global__ __launch_bounds__(256, 2) void gate_img(
    const float* __restrict__ x, const float* __restrict__ arg,
    const char* __restrict__ img, const float* __restrict__ fw,
    const float* __restrict__ bg, float* __restrict__ g2, int fbase)
{
    __shared__ __align__(16) char lds[81920];
    const int tid = threadIdx.x, wid = tid >> 6, lane = tid & 63;
    SWZ_DECODE();
    const int bm0 = bx * 128, bn0 = by * 128;
    const int z = bz, f = fbase + z;
    const float* argf = arg + (size_t)f * 4096 * 1024;
    const char* Bt = img + (size_t)((f * 8 + by) << 6) * 16384;
    const int wr = (wid >> 1) * 64, wc = (wid & 1) * 64;
    const int g = lane >> 4, rl = lane & 15;
    const int goff = ((g ^ ((rl >> 1) & 3)) << 4);
    const int boff = wid * 4096 + lane * 16;
    char* Ac = lds;            char* An = lds + 16384;
    char* Bc0 = lds + 32768;   char* Bc1 = lds + 49152;   char* Bc2 = lds + 65536;

    const int arow = bm0 + (tid >> 2);
    const int akc  = (tid & 3) * 8;
    float ra[2][8];
#define LOADA_G(KT)                                                            \
    {                                                                          \
        int k0 = (KT) * 32 + akc;                                              \
        const float* base = (k0 < 1024) ? x : (argf - 1024);                   \
        const float* s  = base + (size_t)arow * 1024 + k0;                     \
        const float* s2 = base + (size_t)(arow + 64) * 1024 + k0;              \
        *(float4*)&ra[0][0] = ((const float4*)s)[0];                           \
        *(float4*)&ra[0][4] = ((const float4*)s)[1];                           \
        *(float4*)&ra[1][0] = ((const float4*)s2)[0];                          \
        *(float4*)&ra[1][4] = ((const float4*)s2)[1];                          \
    }

    f32x4 acc[4][4];
    f32x4 zero = {0.f, 0.f, 0.f, 0.f};
#pragma unroll
    for (int i = 0; i < 4; ++i)
#pragma unroll
        for (int j = 0; j < 4; ++j) acc[i][j] = zero;

    PIPE_LOOP(64, LOADA_G)
#undef LOADA_G

    const int cg = lane & 15, rg = (lane >> 4) * 4;
    const bool accum = (fbase > 0);
#pragma unroll
    for (int mi = 0; mi < 4; ++mi)
#pragma unroll
        for (int i = 0; i < 4; ++i) {
            int row_out = bm0 + wr + mi * 16 + rg + i;
            float fwv = fw[(size_t)row_out * 4 + f];
#pragma unroll
            for (int ni = 0; ni < 4; ++ni) {
                int col = bn0 + wc + ni * 16 + cg;
                float v = acc[mi][ni][i] + bg[f * 1024 + col];
                float s = fwv / (1.0f + expf(-v));
                size_t off = ((size_t)z * 4096 + row_out) * 1024 + col;
                if (accum) g2[off] += s; else g2[off] = s;
            }
        }
}

// ---------------------------------------------------------------------------
// deproj_part: K-split x4 partials of de_proj = dtab @ Wl[f][2048:3072].
// ---------------------------------------------------------------------------
#define STAGE_WRITE64()                                                        \
    _Pragma("unroll")                                                          \
    for (int i = 0; i < 4; ++i) {                                              \
        int u = tid + i * 256;                                                 \
        int arow = u >> 3, ag = u & 7;                                         \
        bf16x8 H, L; split8(rav[i], H, L);                                     \
        char* dst = lds + arow * 128 + ((ag ^ (arow & 7)) << 4);               \
        *(bf16x8*)dst = H; *(bf16x8*)(dst + 16384) = L;                        \
    }                                                                          \
    _Pragma("unroll")                                                          \
    for (int i = 0; i < 4; ++i) {                                              \
        int u = tid + i * 256;                                                 \
        int bcol = u & 127, bgu = u >> 7;                                      \
        bf16x8 H, L; split8(rbv[i], H, L);                                     \
        char* dst = lds + 32768 + bcol * 128 + ((bgu ^ (bcol & 7)) << 4);      \
        *(bf16x8*)dst = H; *(bf16x8*)(dst + 16384) = L;                        \
    }

#define MFMA64()                                                               \
    _Pragma("unroll")                                                          \
    for (int ks2 = 0; ks2 < 2; ++ks2) {                                        \
        bf16x8 ah[4], al[4], bh[4], bl_[4];                                    \
        _Pragma("unroll")                                                      \
        for (int mi = 0; mi < 4; ++mi) {                                       \
            const char* pa = lds + (wr + mi * 16 + rl) * 128                   \
                             + (((ks2 * 4 + g) ^ (rl & 7)) << 4);              \
            ah[mi] = *(const bf16x8*)pa;                                       \
            al[mi] = *(const bf16x8*)(pa + 16384);                             \
        }                                                                      \
        _Pragma("unroll")                                                      \
        for (int ni = 0; ni < 4; ++ni) {                                       \
            const char* pb = lds + 32768 + (wc + ni * 16 + rl) * 128           \
                             + (((ks2 * 4 + g) ^ (rl & 7)) << 4);              \
            bh[ni]  = *(const bf16x8*)pb;                                      \
            bl_[ni] = *(const bf16x8*)(pb + 16384);                            \
        }                                                                      \
        _Pragma("unroll")                                                      \
        for (int mi = 0; mi < 4; ++mi)                                         \
            _Pragma("unroll")                                                  \
            for (int ni = 0; ni < 4; ++ni) {                                   \
                acc[mi][ni] = __builtin_amdgcn_mfma_f32_16x16x32_bf16(ah[mi], bh[ni],  acc[mi][ni], 0, 0, 0); \
                acc[mi][ni] = __builtin_amdgcn_mfma_f32_16x16x32_bf16(ah[mi], bl_[ni], acc[mi][ni], 0, 0, 0); \
                acc[mi][ni] = __builtin_amdgcn_mfma_f32_16x16x32_bf16(al[mi], bh[ni],  acc[mi][ni], 0, 0, 0); \
            }                                                                  \
    }

__global__ __launch_bounds__(256, 2) void deproj_part(
    const float* __restrict__ dtab, const float* __restrict__ Wl,
    float* __restrict__ pbase)
{
    __shared__ __align__(16) char lds[65536];
    const int tid = threadIdx.x, wid = tid >> 6, lane = tid & 63;
    SWZ_DECODE();
    const int bm0 = bx * 128, bn0 = by * 128;
    const int f = bz & 3, ks = bz >> 2;
    const int akb = ks * 256;
    const float* Bf = Wl + (size_t)f * 3072 * 1024 + (size_t)(2048 + ks * 256) * 1024;
    float* Cp = pbase + (size_t)ks * 2101248 + (size_t)f * 525312;
    const int wr = (wid >> 1) * 64, wc = (wid & 1) * 64;
    const int g = lane >> 4, rl = lane & 15;

    float rav[4][8], rbv[4][8];

#define LOADA_D(KC0)                                                           \
    _Pragma("unroll")                                                          \
    for (int i = 0; i < 4; ++i) {                                              \
        int u = tid + i * 256;                                                 \
        int r = bm0 + (u >> 3); if (r > 512) r = 512;                          \
        const float* s = dtab + (size_t)r * 1024 + akb + (KC0) + (u & 7) * 8;  \
        *(float4*)&rav[i][0] = ((const float4*)s)[0];                          \
        *(float4*)&rav[i][4] = ((const float4*)s)[1];                          \
    }
#define LOADB_D(KC0)                                                           \
    _Pragma("unroll")                                                          \
    for (int i = 0; i < 4; ++i) {                                              \
        int u = tid + i * 256;                                                 \
        int bcol = bn0 + (u & 127);                                            \
        int k0 = (KC0) + (u >> 7) * 8;                                         \
        _Pragma("unroll")                                                      \
        for (int j = 0; j < 8; ++j)                                            \
            rbv[i][j] = Bf[(size_t)(k0 + j) * 1024 + bcol];                    \
    }

    f32x4 acc[4][4];
    f32x4 zero = {0.f, 0.f, 0.f, 0.f};
#pragma unroll
    for (int i = 0; i < 4; ++i)
#pragma unroll
        for (int j = 0; j < 4; ++j) acc[i][j] = zero;

    LOADA_D(0) LOADB_D(0)
    for (int kt = 0; kt < 4; ++kt) {
        STAGE_WRITE64()
        __syncthreads();
        if (kt + 1 < 4) { LOADA_D((kt + 1) * 64) LOADB_D((kt + 1) * 64) }
        MFMA64()
        __syncthreads();
    }
#undef LOADA_D
#undef LOADB_D

    const int cg = lane & 15, rg = (lane >> 4) * 4;
#pragma unroll
    for (int mi = 0; mi < 4; ++mi)
#pragma unroll
        for (int i = 0; i < 4; ++i) {
            int row_out = bm0 + wr + mi * 16 + rg + i;
            if (row_out >= 513) continue;
#pragma unroll
            for (int ni = 0; ni < 4; ++ni) {
                int col = bn0 + wc + ni * 16 + cg;
                Cp[(size_t)row_out * 1024 + col] = acc[mi][ni][i];
            }
        }
}

// de_proj = ((p0 + p1) + p2) + p3  (fixed order, deterministic)
__global__ __launch_bounds__(256) void deproj_reduce(float* __restrict__ p)
{
    const size_t i = ((size_t)blockIdx.x * 256 + threadIdx.x) * 4;
    float4 a = *(float4*)&p[i];
    float4 b = *(const float4*)&p[i + 2101248];
    float4 c = *(const float4*)&p[i + 4202496];
    float4 d = *(const float4*)&p[i + 6303744];
    a.x = ((a.x + b.x) + c.x) + d.x;
    a.y = ((a.y + b.y) + c.y) + d.y;
    a.z = ((a.z + b.z) + c.z) + d.z;
    a.w = ((a.w + b.w) + c.w) + d.w;
    *(float4*)&p[i] = a;
}

// ---------------------------------------------------------------------------
// fw[n][0..3] = softmax(x[n] @ Wsel + bsel)
// ---------------------------------------------------------------------------
__global__ __launch_bounds__(256) void fw_kernel(
    const float* __restrict__ x, const float* __restrict__ Wsel,
    const float* __restrict__ bsel, float* __restrict__ fw)
{
    __shared__ float sred[16];
    const int n = blockIdx.x;
    const int tid = threadIdx.x, w = tid >> 6, lane = tid & 63;

    float4 xv = *(const float4*)&x[(size_t)n * 1024 + tid * 4];
    float pf0 = 0, pf1 = 0, pf2 = 0, pf3 = 0;
    const float* wrp = &Wsel[(size_t)tid * 16];
    pf0 += xv.x * wrp[0];  pf1 += xv.x * wrp[1];  pf2 += xv.x * wrp[2];  pf3 += xv.x * wrp[3];
    pf0 += xv.y * wrp[4];  pf1 += xv.y * wrp[5];  pf2 += xv.y * wrp[6];  pf3 += xv.y * wrp[7];
    pf0 += xv.z * wrp[8];  pf1 += xv.z * wrp[9];  pf2 += xv.z * wrp[10]; pf3 += xv.z * wrp[11];
    pf0 += xv.w * wrp[12]; pf1 += xv.w * wrp[13]; pf2 += xv.w * wrp[14]; pf3 += xv.w * wrp[15];
    for (int o = 32; o; o >>= 1) {
        pf0 += __shfl_xor(pf0, o); pf1 += __shfl_xor(pf1, o);
        pf2 += __shfl_xor(pf2, o); pf3 += __shfl_xor(pf3, o);
    }
    if (lane == 0) { sred[w*4+0] = pf0; sred[w*4+1] = pf1; sred[w*4+2] = pf2; sred[w*4+3] = pf3; }
    __syncthreads();
    if (tid == 0) {
        float s0 = sred[0] + sred[4] + sred[8]  + sred[12] + bsel[0];
        float s1 = sred[1] + sred[5] + sred[9]  + sred[13] + bsel[1];
        float s2 = sred[2] + sred[6] + sred[10] + sred[14] + bsel[2];
        float s3 = sred[3] + sred[7] + sred[11] + sred[15] + bsel[3];
        float mx = fmaxf(fmaxf(s0, s1), fmaxf(s2, s3));
        float e0 = expf(s0 - mx), e1 = expf(s1 - mx), e2 = expf(s2 - mx), e3 = expf(s3 - mx);
        float inv = 1.0f / (e0 + e1 + e2 + e3);
        float4 o = { e0 * inv, e1 * inv, e2 * inv, e3 * inv };
        *(float4*)&fw[(size_t)n * 4] = o;
    }
}

// ---------------------------------------------------------------------------
// h = hpre + xl + de_proj[idx] + bl -> GELU -> LN -> *g+b; arg = sum_k sw*h
// xl aliases the output row (arg[f,n]) — read-before-write within the block.
// ---------------------------------------------------------------------------
__global__ __launch_bounds__(256) void ln_fuse_kernel(
    const float* __restrict__ hpre, const float* __restrict__ de_proj,
    const float* __restrict__ bl, const float* __restrict__ ln_g,
    const float* __restrict__ ln_b, const float* __restrict__ sim,
    const int* __restrict__ topk, float* arg,
    int f, int token_base, const float* xl)
{
    __shared__ float red[4 * 1024];
    const int n = token_base + blockIdx.x;
    const int k = threadIdx.x >> 6, lane = threadIdx.x & 63;
    const float* hrow = hpre + ((size_t)blockIdx.x * 4 + k) * 1024;
    const int t  = n & 1023;
    const int tk = topk[(size_t)n * 4 + k];
    int di = t - tk + 256; di = di < 0 ? 0 : (di > 512 ? 512 : di);
    const float* drow = de_proj + ((size_t)f * 513 + di) * 1024;
    const float* blr = bl + f * 1024;
    const float* gr  = ln_g + f * 1024;
    const float* br  = ln_b + f * 1024;
    const float* xr  = xl + (size_t)n * 1024;

    float4 s4 = *(const float4*)&sim[(size_t)n * 4];
    float smax = fmaxf(fmaxf(s4.x, s4.y), fmaxf(s4.z, s4.w));
    float e0 = expf(s4.x - smax), e1 = expf(s4.y - smax);
    float e2 = expf(s4.z - smax), e3 = expf(s4.w - smax);
    float swk = (k == 0 ? e0 : k == 1 ? e1 : k == 2 ? e2 : e3) / (e0 + e1 + e2 + e3);

    float gv[16];
    float ssum = 0.f;
#pragma unroll
    for (int j = 0; j < 4; ++j) {
        int d4 = lane + j * 64;
        float4 h  = *(const float4*)&hrow[d4 * 4];
        float4 dd = *(const float4*)&drow[d4 * 4];
        float4 bb = *(const float4*)&blr[d4 * 4];
        float4 xv = *(const float4*)&xr[d4 * 4];
        float a0 = gelu_f(h.x + xv.x + dd.x + bb.x);
        float a1 = gelu_f(h.y + xv.y + dd.y + bb.y);
        float a2 = gelu_f(h.z + xv.z + dd.z + bb.z);
        float a3 = gelu_f(h.w + xv.w + dd.w + bb.w);
        gv[j*4+0] = a0; gv[j*4+1] = a1; gv[j*4+2] = a2; gv[j*4+3] = a3;
        ssum += a0 + a1 + a2 + a3;
    }
    for (int o = 32; o; o >>= 1) ssum += __shfl_xor(ssum, o);
    float mu = ssum * 0.0009765625f;
    float vs = 0.f;
#pragma unroll
    for (int i = 0; i < 16; ++i) { float dm = gv[i] - mu; vs += dm * dm; }
    for (int o = 32; o; o >>= 1) vs += __shfl_xor(vs, o);
    float rstd = 1.0f / sqrtf(vs * 0.0009765625f + 1e-5f);
#pragma unroll
    for (int j = 0; j < 4; ++j) {
        int d4 = lane + j * 64;
        float4 g4 = *(const float4*)&gr[d4 * 4];
        float4 b4 = *(const float4*)&br[d4 * 4];
        float4 y;
        y.x = ((gv[j*4+0] - mu) * rstd * g4.x + b4.x) * swk;
        y.y = ((gv[j*4+1] - mu) * rstd * g4.y + b4.y) * swk;
        y.z = ((gv[j*4+2] - mu) * rstd * g4.z + b4.z) * swk;
        y.w = ((gv[j*4+3] - mu) * rstd * g4.w + b4.w) * swk;
        *(float4*)&red[k * 1024 + d4 * 4] = y;
    }
    __syncthreads();
    const int p = threadIdx.x;
    float4 r0 = *(const float4*)&red[0 * 1024 + p * 4];
    float4 r1 = *(const float4*)&red[1 * 1024 + p * 4];
    float4 r2 = *(const float4*)&red[2 * 1024 + p * 4];
    float4 r3 = *(const float4*)&red[3 * 1024 + p * 4];
    float4 o;
    o.x = r0.x + r1.x + r2.x + r3.x;
    o.y = r0.y + r1.y + r2.y + r3.y;
    o.z = r0.z + r1.z + r2.z + r3.z;
    o.w = r0.w + r1.w + r2.w + r3.w;
    *(float4*)&arg[((size_t)f * 4096 + n) * 1024 + p * 4] = o;
}

// ---------------------------------------------------------------------------
// uf = (sum_f fw*arg) * (g2[0]+g2[1]); VQ argmin over 32 codes; gather.
// ---------------------------------------------------------------------------
__global__ __launch_bounds__(256) void final_kernel(
    const float* __restrict__ fw, const float* __restrict__ arg,
    const float* __restrict__ g2, const float* __restrict__ cb,
    float* __restrict__ out)
{
    __shared__ float uf_s[1024];
    __shared__ float score_s[32];
    __shared__ int enc_s;
    const int n = blockIdx.x;
    const int tid = threadIdx.x, w = tid >> 6, lane = tid & 63;

    float4 fwv = *(const float4*)&fw[(size_t)n * 4];
    float fwa[4] = { fwv.x, fwv.y, fwv.z, fwv.w };

    float4 prop = {0, 0, 0, 0};
#pragma unroll
    for (int f = 0; f < 4; ++f) {
        float4 av = *(const float4*)&arg[((size_t)f * 4096 + n) * 1024 + tid * 4];
        prop.x += fwa[f] * av.x; prop.y += fwa[f] * av.y;
        prop.z += fwa[f] * av.z; prop.w += fwa[f] * av.w;
    }
    float4 ga = *(const float4*)&g2[(size_t)n * 1024 + tid * 4];
    float4 gb = *(const float4*)&g2[(size_t)(4096 + n) * 1024 + tid * 4];
    float4 uf;
    uf.x = prop.x * (ga.x + gb.x); uf.y = prop.y * (ga.y + gb.y);
    uf.z = prop.z * (ga.z + gb.z); uf.w = prop.w * (ga.w + gb.w);
    *(float4*)&uf_s[tid * 4] = uf;
    __syncthreads();

#pragma unroll
    for (int cc = 0; cc < 8; ++cc) {
        int c = w * 8 + cc;
        float p = 0.f, q = 0.f;
#pragma unroll
        for (int j = 0; j < 4; ++j) {
            int d4 = lane + j * 64;
            float4 u4 = *(const float4*)&uf_s[d4 * 4];
            float4 c4 = *(const float4*)&cb[(size_t)c * 1024 + d4 * 4];
            p += u4.x * c4.x + u4.y * c4.y + u4.z * c4.z + u4.w * c4.w;
            q += c4.x * c4.x + c4.y * c4.y + c4.z * c4.z + c4.w * c4.w;
        }
        float s = q - 2.0f * p;
        for (int o = 32; o; o >>= 1) s += __shfl_xor(s, o);
        if (lane == 0) score_s[c] = s;
    }
    __syncthreads();
    if (tid < 64) {
        float v; int idx;
        if (lane < 32) { v = score_s[lane]; idx = lane; }
        else           { v = INFINITY;      idx = 1 << 30; }
        for (int o = 16; o; o >>= 1) {
            float ov = __shfl_xor(v, o); int oi = __shfl_xor(idx, o);
            if (ov < v || (ov == v && oi < idx)) { v = ov; idx = oi; }
        }
        if (lane == 0) enc_s = idx;
    }
    __syncthreads();
    const int enc = enc_s;
    float4 o4 = *(const float4*)&cb[(size_t)enc * 1024 + tid * 4];
    *(float4*)&out[(size_t)n * 1024 + tid * 4] = o4;
}

// ---------------------------------------------------------------------------
extern "C" void kernel_launch(void* const* d_in, const int* in_sizes, int n_in,
                              void* d_out, int out_size, void* d_ws, size_t ws_size,
                              hipStream_t stream)
{
    const float* x    = (const float*)d_in[0];
    const float* rf   = (const float*)d_in[1];
    const float* sim  = (const float*)d_in[2];
    const float* Wl   = (const float*)d_in[3];
    const float* bl   = (const float*)d_in[4];
    const float* ln_g = (const float*)d_in[5];
    const float* ln_b = (const float*)d_in[6];
    const float* Wg   = (const float*)d_in[7];
    const float* bg   = (const float*)d_in[8];
    const float* Wsel = (const float*)d_in[9];
    const float* bsel = (const float*)d_in[10];
    const float* dtab = (const float*)d_in[11];
    const float* cb   = (const float*)d_in[12];
    const int*   topk = (const int*)d_in[13];
    float* out = (float*)d_out;
    dim3 blk(256);

    // ws layout (bytes), budget 142,622,720:
    //   arg     @ 0            67,108,864   (xl written in-place, then ln output)
    //   phase B:
    //     de_proj @ 67,108,864  8,404,992   (K-split partials extend into hbuf)
    //     hbuf    @ 75,513,856 33,554,432
    //     Wl1img  @109,068,288 16,777,216
    //     Wl0img  @125,845,504 16,777,216   (ends exactly at budget)
    //   phase C (B pool dead):
    //     Wgimg   @ 67,108,864 33,554,432
    //     g2      @100,663,296 33,554,432
    //     fw      @134,217,728     65,536
    const size_t NEED = 142622720ull;
    if (ws_size < NEED) return;
    char* ws = (char*)d_ws;
    float* arg     = (float*)(ws + 0);
    float* de_proj = (float*)(ws + 67108864);
    float* hbuf    = (float*)(ws + 75513856);
    char*  Wl1img  = ws + 109068288;
    char*  Wl0img  = ws + 125845504;
    char*  Wgimg   = ws + 67108864;
    float* g2      = (float*)(ws + 100663296);
    float* fw      = (float*)(ws + 134217728);

    // 1) de_proj partials (K-split x4, 640 blocks) + deterministic reduce
    deproj_part<<<dim3(5, 8, 16), blk, 0, stream>>>(dtab, Wl, de_proj);
    deproj_reduce<<<2052, blk, 0, stream>>>(de_proj);

    // 2) Wl0 image; xl4: arg[f] = x @ Wl0img[f]  (1024 blocks, image path)
    precvt_img<<<512, blk, 0, stream>>>(Wl, Wl0img, 0, 5, 99);
    gemm_img<<<dim3(32, 8, 4), blk, 0, stream>>>(
        x, 0, Wl0img, 0, arg, (size_t)4096 * 1024);

    // 3) Wl1 image
    precvt_img<<<512, blk, 0, stream>>>(Wl, Wl1img, 1024, 5, 99);

    // 4) per f, per chunk: h GEMM (image path) + fused GELU/LN/softmax-reduce
    for (int f = 0; f < 4; ++f) {
        const float* xlf = arg + (size_t)f * 4096 * 1024;
        for (int ch = 0; ch < 2; ++ch) {
            gemm_img<<<dim3(64, 8, 1), blk, 0, stream>>>(
                rf, ch * 8192, Wl1img, f, hbuf, 0);
            ln_fuse_kernel<<<2048, blk, 0, stream>>>(
                hbuf, de_proj, bl, ln_g, ln_b, sim, topk, arg,
                f, ch * 2048, xlf);
        }
    }

    // 5) Wg image (summed k>=1024) — phase-B pool dead
    precvt_img<<<1024, blk, 0, stream>>>(Wg, Wgimg, 0, 6, 32);

    // 6) fw = softmax(x @ Wsel + bsel)
    fw_kernel<<<4096, blk, 0, stream>>>(x, Wsel, bsel, fw);

    // 7) g2[z] = fw[:,z] * sigmoid([x|arg_z] @ Wg[z] + bg[z]); then += f=z+2
    gate_img<<<dim3(32, 8, 2), blk, 0, stream>>>(x, arg, Wgimg, fw, bg, g2, 0);
    gate_img<<<dim3(32, 8, 2), blk, 0, stream>>>(x, arg, Wgimg, fw, bg, g2, 2);

    // 8) uf = (sum_f fw*arg) * (g2[0]+g2[1]); VQ argmin; codebook gather
    final_kernel<<<4096, blk, 0, stream>>>(fw, arg, g2, cb, out);
}